// Round 10
// baseline (222.338 us; speedup 1.0000x reference)
//
#include <hip/hip_runtime.h>
#include <stdint.h>

#define N_   64
#define C_   64
#define W_   4096
#define F_   64
#define WW_  9
#define OW_  4088        // W_ - WW_ + 1
#define WBLK 128
#define WROWS 136        // WBLK + 8 halo

typedef __bf16 bf16x8 __attribute__((ext_vector_type(8)));
typedef float  f32x4  __attribute__((ext_vector_type(4)));

__device__ __forceinline__ unsigned short f2bf(float f) {
    union { float f; uint32_t u; } v; v.f = f;
    uint32_t u = v.u;
    return (unsigned short)((u + 0x7FFFu + ((u >> 16) & 1u)) >> 16);  // RNE
}

// pack 4 floats -> 4 bf16 (two v_cvt_pk_bf16_f32, RNE)
__device__ __forceinline__ uint2 pk4(float a, float b, float c, float d) {
    uint2 r;
    asm volatile("v_cvt_pk_bf16_f32 %0, %1, %2" : "=v"(r.x) : "v"(a), "v"(b));
    asm volatile("v_cvt_pk_bf16_f32 %0, %1, %2" : "=v"(r.y) : "v"(c), "v"(d));
    return r;
}

// filt fp32 [F][C][WW] -> filtB bf16, fragment-major [t][f0h][m][u][lane][8j]
__global__ __launch_bounds__(256) void prep_filt_k(const float* __restrict__ filt,
                                                   unsigned short* __restrict__ filtB) {
    int id = blockIdx.x * 256 + threadIdx.x;
    if (id < WW_ * F_ * C_) {
        int j    = id & 7;
        int lane = (id >> 3) & 63;
        int u    = (id >> 9) & 1;
        int m    = (id >> 10) & 1;
        int f0h  = (id >> 11) & 1;
        int t    = id >> 12;
        int l15  = lane & 15, lg = lane >> 4;
        int f = f0h * 32 + u * 16 + l15;
        int c = m * 32 + lg * 8 + j;
        filtB[id] = f2bf(filt[(f * C_ + c) * WW_ + t]);
    }
}

// ============ DIAGNOSTIC PROBE: compute core x16, no staging, no big stores ======
// Identical (t,m,s) loop structure / addresses / B-path as conv_k's compute phase.
// LDS zero-filled (deterministic). Repeat loop NOT unrolled; B tap index and A row
// are rotated per-iteration so LICM can't hoist the loads.
__global__ __launch_bounds__(256, 6) void probe_compute_k(const unsigned short* __restrict__ filtB,
                                                          float4* __restrict__ sink) {
    __shared__ unsigned short xs[WROWS * 64];
    const int tid = threadIdx.x;
    for (int i = tid; i < (WROWS * 64) / 8; i += 256)
        reinterpret_cast<uint4*>(xs)[i] = (uint4){0u, 0u, 0u, 0u};
    __syncthreads();

    const int lane = tid & 63;
    const int wv   = tid >> 6;
    const int f0h  = wv & 1;
    const int whb  = (wv >> 1) * 64;
    const int l15  = lane & 15;
    const int lg   = lane >> 4;
    const unsigned short* Bb = filtB + f0h * 2048 + lane * 8;

    f32x4 acc[4][2];
    #pragma unroll
    for (int s = 0; s < 4; ++s) {
        acc[s][0] = (f32x4){0.f, 0.f, 0.f, 0.f};
        acc[s][1] = (f32x4){0.f, 0.f, 0.f, 0.f};
    }

    #pragma unroll 1
    for (int it = 0; it < 16; ++it) {
        const int rx = (it & 1) << 2;                    // row perturbation (stays <136)
        #pragma unroll
        for (int t = 0; t < WW_; ++t) {
            int t2 = t + it;                             // rotate tap -> fresh B address
            if (t2 >= 9) t2 -= 9;
            if (t2 >= 9) t2 -= 9;
            #pragma unroll
            for (int m = 0; m < 2; ++m) {
                bf16x8 b0 = *reinterpret_cast<const bf16x8*>(Bb + t2 * 4096 + m * 1024);
                bf16x8 b1 = *reinterpret_cast<const bf16x8*>(Bb + t2 * 4096 + m * 1024 + 512);
                #pragma unroll
                for (int s = 0; s < 4; ++s) {
                    int row   = (whb + s * 16 + l15 + t) ^ rx;       // <= 135
                    int chunk = ((m << 2) | lg) ^ (row & 7);
                    bf16x8 a  = *reinterpret_cast<const bf16x8*>(&xs[row * 64 + chunk * 8]);
                    acc[s][0] = __builtin_amdgcn_mfma_f32_16x16x32_bf16(a, b0, acc[s][0], 0, 0, 0);
                    acc[s][1] = __builtin_amdgcn_mfma_f32_16x16x32_bf16(a, b1, acc[s][1], 0, 0, 0);
                }
            }
        }
    }
    float4 o;
    o.x = acc[0][0][0] + acc[1][0][1];
    o.y = acc[2][0][2] + acc[3][0][3];
    o.z = acc[0][1][0] + acc[1][1][1];
    o.w = acc[2][1][2] + acc[3][1][3];
    sink[((size_t)blockIdx.y * gridDim.x + blockIdx.x) * 256 + tid] = o;   // zeros, 8 MB
}

// ===================== REAL KERNEL: round-7 best (44 us), unchanged =====================
__global__ __launch_bounds__(256, 6) void conv_k(const float* __restrict__ x,
                                                 const unsigned short* __restrict__ filtB,
                                                 const float* __restrict__ bias,
                                                 float* __restrict__ out) {
    __shared__ unsigned short xs[WROWS * 64];   // 17408 B, swizzled rows of 128B

    const int tid  = threadIdx.x;
    const int lane = tid & 63;
    const int wv   = tid >> 6;
    const int n    = blockIdx.y;
    const int w0   = blockIdx.x * WBLK;

    {
        const int c4 = (wv << 4) + (((tid >> 4) & 3) << 2);
        const int wq = (tid & 15) << 2;
        const int cg = c4 >> 3;
        const int cs = c4 & 7;
        const float* xb = x + ((size_t)(n * C_ + c4)) * W_ + w0;
        #pragma unroll
        for (int j = 0; j < 2; ++j) {
            const int wl = wq + j * 64;
            float4 r0 = *reinterpret_cast<const float4*>(xb + 0 * W_ + wl);
            float4 r1 = *reinterpret_cast<const float4*>(xb + 1 * W_ + wl);
            float4 r2 = *reinterpret_cast<const float4*>(xb + 2 * W_ + wl);
            float4 r3 = *reinterpret_cast<const float4*>(xb + 3 * W_ + wl);
            const float* p0 = &r0.x; const float* p1 = &r1.x;
            const float* p2 = &r2.x; const float* p3 = &r3.x;
            #pragma unroll
            for (int jj = 0; jj < 4; ++jj) {
                int w = wl + jj;
                uint2 u2 = pk4(p0[jj], p1[jj], p2[jj], p3[jj]);
                *reinterpret_cast<uint2*>(&xs[w * 64 + ((cg ^ (w & 7)) << 3) + cs]) = u2;
            }
        }
        if (tid < 32) {
            const int hc4 = (tid & 15) << 2;
            const int hwl = 128 + ((tid >> 4) << 2);
            const int hcg = hc4 >> 3;
            const int hcs = hc4 & 7;
            #pragma unroll
            for (int jj = 0; jj < 4; ++jj) {
                int w  = hwl + jj;
                int gw = w0 + w;
                float a0 = 0.f, a1 = 0.f, a2 = 0.f, a3 = 0.f;
                if (gw < W_) {
                    const float* hp = x + ((size_t)(n * C_ + hc4)) * W_ + gw;
                    a0 = hp[0];
                    a1 = hp[(size_t)W_];
                    a2 = hp[(size_t)2 * W_];
                    a3 = hp[(size_t)3 * W_];
                }
                uint2 u2 = pk4(a0, a1, a2, a3);
                *reinterpret_cast<uint2*>(&xs[w * 64 + ((hcg ^ (w & 7)) << 3) + hcs]) = u2;
            }
        }
    }
    __syncthreads();

    const int f0h = wv & 1;
    const int whb = (wv >> 1) * 64;
    const int l15 = lane & 15;
    const int lg  = lane >> 4;

    const unsigned short* Bb = filtB + f0h * 2048 + lane * 8;
    const float bv0 = 64.0f * bias[f0h * 32 + l15];
    const float bv1 = 64.0f * bias[f0h * 32 + 16 + l15];

    f32x4 acc[4][2];
    #pragma unroll
    for (int s = 0; s < 4; ++s) {
        acc[s][0] = (f32x4){0.f, 0.f, 0.f, 0.f};
        acc[s][1] = (f32x4){0.f, 0.f, 0.f, 0.f};
    }

    #pragma unroll
    for (int t = 0; t < WW_; ++t) {
        #pragma unroll
        for (int m = 0; m < 2; ++m) {
            bf16x8 b0 = *reinterpret_cast<const bf16x8*>(Bb + t * 4096 + m * 1024);
            bf16x8 b1 = *reinterpret_cast<const bf16x8*>(Bb + t * 4096 + m * 1024 + 512);
            #pragma unroll
            for (int s = 0; s < 4; ++s) {
                int row   = whb + s * 16 + l15 + t;
                int chunk = ((m << 2) | lg) ^ (row & 7);
                bf16x8 a  = *reinterpret_cast<const bf16x8*>(&xs[row * 64 + chunk * 8]);
                acc[s][0] = __builtin_amdgcn_mfma_f32_16x16x32_bf16(a, b0, acc[s][0], 0, 0, 0);
                acc[s][1] = __builtin_amdgcn_mfma_f32_16x16x32_bf16(a, b1, acc[s][1], 0, 0, 0);
            }
        }
    }

    const int fb = f0h * 32 + l15;
    #pragma unroll
    for (int s = 0; s < 4; ++s) {
        int wg = w0 + whb + s * 16 + lg * 4;
        if (wg < OW_) {
            float4 o0, o1;
            o0.x = acc[s][0][0] + bv0; o0.y = acc[s][0][1] + bv0;
            o0.z = acc[s][0][2] + bv0; o0.w = acc[s][0][3] + bv0;
            o1.x = acc[s][1][0] + bv1; o1.y = acc[s][1][1] + bv1;
            o1.z = acc[s][1][2] + bv1; o1.w = acc[s][1][3] + bv1;
            *reinterpret_cast<float4*>(out + ((size_t)(n * F_ + fb) * OW_ + wg))      = o0;
            *reinterpret_cast<float4*>(out + ((size_t)(n * F_ + fb + 16) * OW_ + wg)) = o1;
        }
    }
}

extern "C" void kernel_launch(void* const* d_in, const int* in_sizes, int n_in,
                              void* d_out, int out_size, void* d_ws, size_t ws_size,
                              hipStream_t stream) {
    const float* x    = (const float*)d_in[0];
    const float* filt = (const float*)d_in[1];
    const float* bias = (const float*)d_in[2];
    float* out        = (float*)d_out;

    unsigned short* filtB = (unsigned short*)d_ws;   // 73728 B at offset 0

    prep_filt_k<<<(WW_ * F_ * C_ + 255) / 256, 256, 0, stream>>>(filt, filtB);

    dim3 grid(W_ / WBLK, N_);   // 32 x 64 = 2048 blocks

    // diagnostic probe (writes zeros into d_ws at +1MB; d_out untouched)
    if (ws_size >= (1u << 20) + (size_t)2048 * 256 * 16) {
        float4* sink = (float4*)((char*)d_ws + (1u << 20));
        probe_compute_k<<<grid, 256, 0, stream>>>(filtB, sink);
    }

    // real kernel last: writes every element of d_out
    conv_k<<<grid, 256, 0, stream>>>(x, filtB, bias, out);
}

// Round 11
// 81.500 us; speedup vs baseline: 2.7281x; 2.7281x over previous
//
#include <hip/hip_runtime.h>
#include <stdint.h>

#define N_   64
#define C_   64
#define W_   4096
#define F_   64
#define WW_  9
#define OW_  4088        // W_ - WW_ + 1
#define WBLK 128
#define WROWS 136        // WBLK + 8 halo
#define TPB  4           // tiles per block (one 512-w strip)

typedef __bf16 bf16x8 __attribute__((ext_vector_type(8)));
typedef float  f32x4  __attribute__((ext_vector_type(4)));

__device__ __forceinline__ unsigned short f2bf(float f) {
    union { float f; uint32_t u; } v; v.f = f;
    uint32_t u = v.u;
    return (unsigned short)((u + 0x7FFFu + ((u >> 16) & 1u)) >> 16);  // RNE
}

// pack 4 floats -> 4 bf16 (two v_cvt_pk_bf16_f32, RNE)
__device__ __forceinline__ uint2 pk4(float a, float b, float c, float d) {
    uint2 r;
    asm volatile("v_cvt_pk_bf16_f32 %0, %1, %2" : "=v"(r.x) : "v"(a), "v"(b));
    asm volatile("v_cvt_pk_bf16_f32 %0, %1, %2" : "=v"(r.y) : "v"(c), "v"(d));
    return r;
}

// filt fp32 [F][C][WW] -> filtB bf16, fragment-major [t][f0h][m][u][lane][8j]
//   f = f0h*32 + u*16 + (lane&15),  c = m*32 + (lane>>4)*8 + j
__global__ __launch_bounds__(256) void prep_filt_k(const float* __restrict__ filt,
                                                   unsigned short* __restrict__ filtB) {
    int id = blockIdx.x * 256 + threadIdx.x;
    if (id < WW_ * F_ * C_) {
        int j    = id & 7;
        int lane = (id >> 3) & 63;
        int u    = (id >> 9) & 1;
        int m    = (id >> 10) & 1;
        int f0h  = (id >> 11) & 1;
        int t    = id >> 12;
        int l15  = lane & 15, lg = lane >> 4;
        int f = f0h * 32 + u * 16 + l15;
        int c = m * 32 + lg * 8 + j;
        filtB[id] = f2bf(filt[(f * C_ + c) * WW_ + t]);
    }
}

// Producer/consumer wave specialization. Block = 512 thr = 8 waves:
//   waves 0-3 CONSUMERS: R7's exact compute+store (64w x 32f quadrants).
//   waves 4-7 PRODUCERS: R7's exact staging map (transpose+convert+swizzled LDS write).
// Block owns a 512-w strip (4 tiles); LDS double-buffered. Per tile iteration,
// producers stage tile i+1 while consumers compute tile i -> true stage/compute
// overlap with NO registers held across barriers (R9's spill mode eliminated).
__global__ __launch_bounds__(512, 4) void conv_k(const float* __restrict__ x,
                                                 const unsigned short* __restrict__ filtB,
                                                 const float* __restrict__ bias,
                                                 float* __restrict__ out) {
    __shared__ unsigned short xs[2][WROWS * 64];   // 2 x 17408 B, swizzled 128B rows

    const int tid   = threadIdx.x;                 // 0..511
    const int n     = blockIdx.y;
    const int wbase = blockIdx.x * (WBLK * TPB);
    const bool producer = (tid >= 256);

    // ---- producer constants (R7 staging map on p = tid-256) ----
    const int p   = tid & 255;
    const int pwv = p >> 6;
    const int c4  = (pwv << 4) + (((p >> 4) & 3) << 2);
    const int wq  = (p & 15) << 2;
    const int cg  = c4 >> 3;
    const int cs  = c4 & 7;
    const float* xb = x + ((size_t)(n * C_ + c4)) * W_;
    const int hc4 = (p & 15) << 2;                 // halo (p<32)
    const int hwl = 128 + ((p >> 4) << 2);
    const int hcg = hc4 >> 3;
    const int hcs = hc4 & 7;
    const float* hb = x + ((size_t)(n * C_ + hc4)) * W_;

    auto STAGE = [&](int b, int w0) {
        unsigned short* dst = xs[b];
        #pragma unroll
        for (int j = 0; j < 2; ++j) {
            const int wl = wq + j * 64;            // w0+wl+3 <= 4095: in-bounds
            float4 r0 = *reinterpret_cast<const float4*>(xb + 0 * W_ + w0 + wl);
            float4 r1 = *reinterpret_cast<const float4*>(xb + 1 * W_ + w0 + wl);
            float4 r2 = *reinterpret_cast<const float4*>(xb + 2 * W_ + w0 + wl);
            float4 r3 = *reinterpret_cast<const float4*>(xb + 3 * W_ + w0 + wl);
            const float* p0 = &r0.x; const float* p1 = &r1.x;
            const float* p2 = &r2.x; const float* p3 = &r3.x;
            #pragma unroll
            for (int jj = 0; jj < 4; ++jj) {
                int w = wl + jj;
                uint2 u2 = pk4(p0[jj], p1[jj], p2[jj], p3[jj]);
                *reinterpret_cast<uint2*>(&dst[w * 64 + ((cg ^ (w & 7)) << 3) + cs]) = u2;
            }
        }
        if (p < 32) {                              // halo w=128..135, guarded (last tile)
            #pragma unroll
            for (int jj = 0; jj < 4; ++jj) {
                int w  = hwl + jj;
                int gw = w0 + w;
                float a0 = 0.f, a1 = 0.f, a2 = 0.f, a3 = 0.f;
                if (gw < W_) {
                    a0 = hb[gw];
                    a1 = hb[gw + (size_t)W_];
                    a2 = hb[gw + (size_t)2 * W_];
                    a3 = hb[gw + (size_t)3 * W_];
                }
                uint2 u2 = pk4(a0, a1, a2, a3);
                *reinterpret_cast<uint2*>(&dst[w * 64 + ((hcg ^ (w & 7)) << 3) + hcs]) = u2;
            }
        }
    };

    // ---- consumer constants (R7 compute geometry on tid 0..255) ----
    const int lane = tid & 63;
    const int wv   = (tid >> 6) & 3;
    const int f0h  = wv & 1;
    const int whb  = (wv >> 1) * 64;
    const int l15  = lane & 15;
    const int lg   = lane >> 4;
    const unsigned short* Bb = filtB + f0h * 2048 + lane * 8;
    const float bv0 = 64.0f * bias[f0h * 32 + l15];        // ref adds bias per channel -> C*bias
    const float bv1 = 64.0f * bias[f0h * 32 + 16 + l15];

    auto COMPUTE = [&](int b, int w0) {
        const unsigned short* src = xs[b];
        f32x4 acc[4][2];
        #pragma unroll
        for (int s = 0; s < 4; ++s) {
            acc[s][0] = (f32x4){0.f, 0.f, 0.f, 0.f};
            acc[s][1] = (f32x4){0.f, 0.f, 0.f, 0.f};
        }
        #pragma unroll
        for (int t = 0; t < WW_; ++t) {
            #pragma unroll
            for (int m = 0; m < 2; ++m) {
                bf16x8 b0 = *reinterpret_cast<const bf16x8*>(Bb + t * 4096 + m * 1024);
                bf16x8 b1 = *reinterpret_cast<const bf16x8*>(Bb + t * 4096 + m * 1024 + 512);
                #pragma unroll
                for (int s = 0; s < 4; ++s) {
                    int row   = whb + s * 16 + l15 + t;              // <= 135
                    int chunk = ((m << 2) | lg) ^ (row & 7);
                    bf16x8 a  = *reinterpret_cast<const bf16x8*>(&src[row * 64 + chunk * 8]);
                    acc[s][0] = __builtin_amdgcn_mfma_f32_16x16x32_bf16(a, b0, acc[s][0], 0, 0, 0);
                    acc[s][1] = __builtin_amdgcn_mfma_f32_16x16x32_bf16(a, b1, acc[s][1], 0, 0, 0);
                }
            }
        }
        const int fb = f0h * 32 + l15;
        #pragma unroll
        for (int s = 0; s < 4; ++s) {
            int wg = w0 + whb + s * 16 + lg * 4;
            if (wg < OW_) {                    // wg%4==0, OW_%4==0 -> whole float4 in-range
                float4 o0, o1;
                o0.x = acc[s][0][0] + bv0; o0.y = acc[s][0][1] + bv0;
                o0.z = acc[s][0][2] + bv0; o0.w = acc[s][0][3] + bv0;
                o1.x = acc[s][1][0] + bv1; o1.y = acc[s][1][1] + bv1;
                o1.z = acc[s][1][2] + bv1; o1.w = acc[s][1][3] + bv1;
                *reinterpret_cast<float4*>(out + ((size_t)(n * F_ + fb) * OW_ + wg))      = o0;
                *reinterpret_cast<float4*>(out + ((size_t)(n * F_ + fb + 16) * OW_ + wg)) = o1;
            }
        }
    };

    // ---- pipeline: barriers are convergent (outside the role split) ----
    // Ledger per iter i: consumers read xs[i&1] (written iter i-1, pre-barrier);
    // producers write xs[(i+1)&1] (last read by consumers iter i-1, pre-barrier).
    if (producer) STAGE(0, wbase);
    __syncthreads();
    #pragma unroll 1
    for (int i = 0; i < TPB; ++i) {
        if (producer) {
            if (i + 1 < TPB) STAGE((i + 1) & 1, wbase + (i + 1) * WBLK);
        } else {
            COMPUTE(i & 1, wbase + i * WBLK);
        }
        __syncthreads();
    }
}

extern "C" void kernel_launch(void* const* d_in, const int* in_sizes, int n_in,
                              void* d_out, int out_size, void* d_ws, size_t ws_size,
                              hipStream_t stream) {
    const float* x    = (const float*)d_in[0];
    const float* filt = (const float*)d_in[1];
    const float* bias = (const float*)d_in[2];
    float* out        = (float*)d_out;

    unsigned short* filtB = (unsigned short*)d_ws;   // 9*64*64 bf16 = 73728 B

    prep_filt_k<<<(WW_ * F_ * C_ + 255) / 256, 256, 0, stream>>>(filt, filtB);

    dim3 grid(W_ / (WBLK * TPB), N_);   // 8 x 64 = 512 blocks of 512 thr, 2/CU
    conv_k<<<grid, 512, 0, stream>>>(x, filtB, bias, out);
}

// Round 12
// 61.789 us; speedup vs baseline: 3.5983x; 1.3190x over previous
//
#include <hip/hip_runtime.h>
#include <stdint.h>

#define N_   64
#define C_   64
#define W_   4096
#define F_   64
#define WW_  9
#define OW_  4088        // W_ - WW_ + 1
#define WBLK 128
#define WROWS 136        // WBLK + 8 halo
#define TPB  4           // tiles per block (one 512-w strip)

typedef __bf16 bf16x8 __attribute__((ext_vector_type(8)));
typedef float  f32x4  __attribute__((ext_vector_type(4)));

__device__ __forceinline__ unsigned short f2bf(float f) {
    union { float f; uint32_t u; } v; v.f = f;
    uint32_t u = v.u;
    return (unsigned short)((u + 0x7FFFu + ((u >> 16) & 1u)) >> 16);  // RNE
}

// pack 4 floats -> 4 bf16 (two v_cvt_pk_bf16_f32, RNE)
__device__ __forceinline__ uint2 pk4(float a, float b, float c, float d) {
    uint2 r;
    asm volatile("v_cvt_pk_bf16_f32 %0, %1, %2" : "=v"(r.x) : "v"(a), "v"(b));
    asm volatile("v_cvt_pk_bf16_f32 %0, %1, %2" : "=v"(r.y) : "v"(c), "v"(d));
    return r;
}

// filt fp32 [F][C][WW] -> filtB bf16, fragment-major [t][f0h][m][u][lane][8j]
//   f = f0h*32 + u*16 + (lane&15),  c = m*32 + (lane>>4)*8 + j
__global__ __launch_bounds__(256) void prep_filt_k(const float* __restrict__ filt,
                                                   unsigned short* __restrict__ filtB) {
    int id = blockIdx.x * 256 + threadIdx.x;
    if (id < WW_ * F_ * C_) {
        int j    = id & 7;
        int lane = (id >> 3) & 63;
        int u    = (id >> 9) & 1;
        int m    = (id >> 10) & 1;
        int f0h  = (id >> 11) & 1;
        int t    = id >> 12;
        int l15  = lane & 15, lg = lane >> 4;
        int f = f0h * 32 + u * 16 + l15;
        int c = m * 32 + lg * 8 + j;
        filtB[id] = f2bf(filt[(f * C_ + c) * WW_ + t]);
    }
}

// Producer/consumer wave specialization (round-11 structure, register budget FIXED).
// Block = 512 thr = 8 waves: waves 0-3 CONSUMERS (R7 compute+store), waves 4-7
// PRODUCERS (R7 staging). LDS double-buffered; producers stage tile i+1 while
// consumers compute tile i. __launch_bounds__(512,2): VGPR cap >=128 under either
// launch_bounds semantics (R11's (512,4) forced cap 64 -> spill -> +147MB traffic).
__global__ __launch_bounds__(512, 2) void conv_k(const float* __restrict__ x,
                                                 const unsigned short* __restrict__ filtB,
                                                 const float* __restrict__ bias,
                                                 float* __restrict__ out) {
    __shared__ unsigned short xs[2][WROWS * 64];   // 2 x 17408 B, swizzled 128B rows

    const int tid   = threadIdx.x;                 // 0..511
    const int n     = blockIdx.y;
    const int wbase = blockIdx.x * (WBLK * TPB);
    const bool producer = (tid >= 256);

    // ---- producer constants (R7 staging map on p = tid-256) ----
    const int p   = tid & 255;
    const int pwv = p >> 6;
    const int c4  = (pwv << 4) + (((p >> 4) & 3) << 2);
    const int wq  = (p & 15) << 2;
    const int cg  = c4 >> 3;
    const int cs  = c4 & 7;
    const float* xb = x + ((size_t)(n * C_ + c4)) * W_;
    const int hc4 = (p & 15) << 2;                 // halo (p<32)
    const int hwl = 128 + ((p >> 4) << 2);
    const int hcg = hc4 >> 3;
    const int hcs = hc4 & 7;
    const float* hb = x + ((size_t)(n * C_ + hc4)) * W_;

    auto STAGE = [&](int b, int w0) {
        unsigned short* dst = xs[b];
        #pragma unroll
        for (int j = 0; j < 2; ++j) {
            const int wl = wq + j * 64;            // w0+wl+3 <= 4095: in-bounds
            float4 r0 = *reinterpret_cast<const float4*>(xb + 0 * W_ + w0 + wl);
            float4 r1 = *reinterpret_cast<const float4*>(xb + 1 * W_ + w0 + wl);
            float4 r2 = *reinterpret_cast<const float4*>(xb + 2 * W_ + w0 + wl);
            float4 r3 = *reinterpret_cast<const float4*>(xb + 3 * W_ + w0 + wl);
            const float* p0 = &r0.x; const float* p1 = &r1.x;
            const float* p2 = &r2.x; const float* p3 = &r3.x;
            #pragma unroll
            for (int jj = 0; jj < 4; ++jj) {
                int w = wl + jj;
                uint2 u2 = pk4(p0[jj], p1[jj], p2[jj], p3[jj]);
                *reinterpret_cast<uint2*>(&dst[w * 64 + ((cg ^ (w & 7)) << 3) + cs]) = u2;
            }
        }
        if (p < 32) {                              // halo w=128..135, guarded (last tile)
            #pragma unroll
            for (int jj = 0; jj < 4; ++jj) {
                int w  = hwl + jj;
                int gw = w0 + w;
                float a0 = 0.f, a1 = 0.f, a2 = 0.f, a3 = 0.f;
                if (gw < W_) {
                    a0 = hb[gw];
                    a1 = hb[gw + (size_t)W_];
                    a2 = hb[gw + (size_t)2 * W_];
                    a3 = hb[gw + (size_t)3 * W_];
                }
                uint2 u2 = pk4(a0, a1, a2, a3);
                *reinterpret_cast<uint2*>(&dst[w * 64 + ((hcg ^ (w & 7)) << 3) + hcs]) = u2;
            }
        }
    };

    // ---- consumer constants (R7 compute geometry on tid 0..255) ----
    const int lane = tid & 63;
    const int wv   = (tid >> 6) & 3;
    const int f0h  = wv & 1;
    const int whb  = (wv >> 1) * 64;
    const int l15  = lane & 15;
    const int lg   = lane >> 4;
    const unsigned short* Bb = filtB + f0h * 2048 + lane * 8;
    const float bv0 = 64.0f * bias[f0h * 32 + l15];        // ref adds bias per channel -> C*bias
    const float bv1 = 64.0f * bias[f0h * 32 + 16 + l15];

    auto COMPUTE = [&](int b, int w0) {
        const unsigned short* src = xs[b];
        f32x4 acc[4][2];
        #pragma unroll
        for (int s = 0; s < 4; ++s) {
            acc[s][0] = (f32x4){0.f, 0.f, 0.f, 0.f};
            acc[s][1] = (f32x4){0.f, 0.f, 0.f, 0.f};
        }
        #pragma unroll
        for (int t = 0; t < WW_; ++t) {
            #pragma unroll
            for (int m = 0; m < 2; ++m) {
                bf16x8 b0 = *reinterpret_cast<const bf16x8*>(Bb + t * 4096 + m * 1024);
                bf16x8 b1 = *reinterpret_cast<const bf16x8*>(Bb + t * 4096 + m * 1024 + 512);
                bf16x8 a[4];
                #pragma unroll
                for (int s = 0; s < 4; ++s) {
                    int row   = whb + s * 16 + l15 + t;              // <= 135
                    int chunk = ((m << 2) | lg) ^ (row & 7);
                    a[s] = *reinterpret_cast<const bf16x8*>(&src[row * 64 + chunk * 8]);
                }
                __builtin_amdgcn_s_setprio(1);     // T5: role-split regime (producers issue VMEM)
                #pragma unroll
                for (int s = 0; s < 4; ++s) {
                    acc[s][0] = __builtin_amdgcn_mfma_f32_16x16x32_bf16(a[s], b0, acc[s][0], 0, 0, 0);
                    acc[s][1] = __builtin_amdgcn_mfma_f32_16x16x32_bf16(a[s], b1, acc[s][1], 0, 0, 0);
                }
                __builtin_amdgcn_s_setprio(0);
            }
        }
        const int fb = f0h * 32 + l15;
        #pragma unroll
        for (int s = 0; s < 4; ++s) {
            int wg = w0 + whb + s * 16 + lg * 4;
            if (wg < OW_) {                    // wg%4==0, OW_%4==0 -> whole float4 in-range
                float4 o0, o1;
                o0.x = acc[s][0][0] + bv0; o0.y = acc[s][0][1] + bv0;
                o0.z = acc[s][0][2] + bv0; o0.w = acc[s][0][3] + bv0;
                o1.x = acc[s][1][0] + bv1; o1.y = acc[s][1][1] + bv1;
                o1.z = acc[s][1][2] + bv1; o1.w = acc[s][1][3] + bv1;
                *reinterpret_cast<float4*>(out + ((size_t)(n * F_ + fb) * OW_ + wg))      = o0;
                *reinterpret_cast<float4*>(out + ((size_t)(n * F_ + fb + 16) * OW_ + wg)) = o1;
            }
        }
    };

    // ---- pipeline: barriers are convergent (outside the role split) ----
    // Ledger per iter i: consumers read xs[i&1] (written iter i-1, pre-barrier);
    // producers write xs[(i+1)&1] (last read by consumers iter i-1, pre-barrier).
    if (producer) STAGE(0, wbase);
    __syncthreads();
    #pragma unroll 1
    for (int i = 0; i < TPB; ++i) {
        if (producer) {
            if (i + 1 < TPB) STAGE((i + 1) & 1, wbase + (i + 1) * WBLK);
        } else {
            COMPUTE(i & 1, wbase + i * WBLK);
        }
        __syncthreads();
    }
}

extern "C" void kernel_launch(void* const* d_in, const int* in_sizes, int n_in,
                              void* d_out, int out_size, void* d_ws, size_t ws_size,
                              hipStream_t stream) {
    const float* x    = (const float*)d_in[0];
    const float* filt = (const float*)d_in[1];
    const float* bias = (const float*)d_in[2];
    float* out        = (float*)d_out;

    unsigned short* filtB = (unsigned short*)d_ws;   // 9*64*64 bf16 = 73728 B

    prep_filt_k<<<(WW_ * F_ * C_ + 255) / 256, 256, 0, stream>>>(filt, filtB);

    dim3 grid(W_ / (WBLK * TPB), N_);   // 8 x 64 = 512 blocks of 512 thr, 2/CU
    conv_k<<<grid, 512, 0, stream>>>(x, filtB, bias, out);
}